// Round 5
// baseline (95.874 us; speedup 1.0000x reference)
//
#include <hip/hip_runtime.h>

// TensorRelaxationPooling: B=8, T=4096, D=128, NB=32, STRIDE=2
//   z1 = 0.5*G*(X@E + bx), z2 = X@F + by   (scale folded into z1 at LDS write)
//   out[p] = z1[2p] (x) z2[2p] + z1[2p+1] (x) z2[2p+1]   -> [16384, 1024] fp32
//
// R5 = R4 structure (measured best, 95.0 us) with VALU-issue reduction:
//   - GEMM inner loop + epilogue in float2 -> v_pk_fma_f32 (halves FMA issue)
//   - 0.5*G folded into z1 at LDS-write time (epilogue loses 4 muls/frame)
// Everything else (tiles, strides, barriers, block-interleaved epilogue) is
// identical to R4 -- R2/R3 proved the epilogue partitioning dominates.

#define DIN 128
#define NB_ 32

typedef float v2f __attribute__((ext_vector_type(2)));

constexpr int FR   = 64;   // raw frames per block
constexpr int POOL = 32;   // pooled frames per block
constexpr int SWS  = 68;   // W row stride (floats)
constexpr int SXS  = 132;  // X-tile row stride (floats)
constexpr int SZS  = 68;   // Z row stride (floats)
constexpr int NBLK = (8 * 4096) / FR;  // 512

__global__ __launch_bounds__(256) void trp_fused(
    const float* __restrict__ X, const float* __restrict__ E,
    const float* __restrict__ F, const float* __restrict__ G,
    const float* __restrict__ bx, const float* __restrict__ by,
    float* __restrict__ out)
{
    __shared__ __align__(16) float sw[DIN * SWS];  // W = [E|F], 34.8 KB
    __shared__ __align__(16) float sxz[FR * SXS];  // X tile; Z overlays. 33.8 KB

    const int tid = threadIdx.x;
    const int blk = blockIdx.x;

    // --- hoisted tiny global loads (latency hides under staging+GEMM) ---
    const int n0 = (tid & 15) * 4;   // basis col base (0..60), z1|z2 concat
    float bias[4], scale;
    if (n0 < NB_) { *(float4*)bias = *(const float4*)(bx + n0);       scale = 0.5f * G[0]; }
    else          { *(float4*)bias = *(const float4*)(by + n0 - NB_); scale = 1.0f; }

    // --- stage W = [E|F]: 2048 float4, 8 per thread ---
    #pragma unroll
    for (int it = 0; it < 8; ++it) {
        int v = tid + 256 * it;
        int d = v >> 4, c = v & 15;
        const float* src = (c < 8) ? (E + d * NB_ + c * 4)
                                   : (F + d * NB_ + (c - 8) * 4);
        *(float4*)&sw[d * SWS + c * 4] = *(const float4*)src;
    }
    // --- stage X tile (64 frames contiguous in global) ---
    const float* xb = X + (size_t)blk * FR * DIN;
    #pragma unroll
    for (int it = 0; it < 8; ++it) {
        int v = tid + 256 * it;
        int f = v >> 5, dc = v & 31;
        *(float4*)&sxz[f * SXS + dc * 4] = *(const float4*)(xb + f * DIN + dc * 4);
    }
    __syncthreads();

    // --- register-tiled GEMM: thread = 4 frames x 4 cols, packed fp32 ---
    const int f0 = (tid >> 4) * 4;

    v2f acc[4][2];
    #pragma unroll
    for (int q = 0; q < 4; ++q) {
        acc[q][0] = (v2f)(0.f);
        acc[q][1] = (v2f)(0.f);
    }

    #pragma unroll 2
    for (int dc = 0; dc < DIN / 4; ++dc) {
        const int d4 = dc * 4;
        v2f w2[4][2];
        #pragma unroll
        for (int r = 0; r < 4; ++r) {
            float4 wv = *(const float4*)&sw[(d4 + r) * SWS + n0];
            w2[r][0] = (v2f){wv.x, wv.y};
            w2[r][1] = (v2f){wv.z, wv.w};
        }
        #pragma unroll
        for (int q = 0; q < 4; ++q) {
            float4 xv = *(const float4*)&sxz[(f0 + q) * SXS + d4];
            float xr[4] = {xv.x, xv.y, xv.z, xv.w};
            #pragma unroll
            for (int r = 0; r < 4; ++r) {
                v2f xbc = (v2f){xr[r], xr[r]};
                acc[q][0] = __builtin_elementwise_fma(xbc, w2[r][0], acc[q][0]);
                acc[q][1] = __builtin_elementwise_fma(xbc, w2[r][1], acc[q][1]);
            }
        }
    }

    // --- bias + scale (0.5*G folded into z1 half), overlay Z (stride 68) ---
    const v2f b2l = (v2f){bias[0], bias[1]};
    const v2f b2h = (v2f){bias[2], bias[3]};
    const v2f s2  = (v2f){scale, scale};
    __syncthreads();  // all GEMM reads of sxz done before overwrite as Z
    #pragma unroll
    for (int q = 0; q < 4; ++q) {
        v2f zl = (acc[q][0] + b2l) * s2;
        v2f zh = (acc[q][1] + b2h) * s2;
        float4 z = {zl.x, zl.y, zh.x, zh.y};
        *(float4*)&sxz[(f0 + q) * SZS + n0] = z;
    }
    __syncthreads();

    // --- epilogue: outer products + pair pooling, block-interleaved stores ---
    const int i = tid >> 3;
    const int j = (tid & 7) * 4;
    float4* outv = (float4*)out + (size_t)blk * (POOL * 256) + tid;
    #pragma unroll 4
    for (int p = 0; p < POOL; ++p) {
        const float* zr0 = &sxz[(2 * p) * SZS];
        const float* zr1 = zr0 + SZS;
        float a0 = zr0[i];                           // z1 (pre-scaled) frame 2p
        float a1 = zr1[i];                           // z1 frame 2p+1
        float4 v0 = *(const float4*)&zr0[NB_ + j];   // z2 frame 2p
        float4 v1 = *(const float4*)&zr1[NB_ + j];   // z2 frame 2p+1
        v2f a0v = (v2f){a0, a0}, a1v = (v2f){a1, a1};
        v2f v0l = (v2f){v0.x, v0.y}, v0h = (v2f){v0.z, v0.w};
        v2f v1l = (v2f){v1.x, v1.y}, v1h = (v2f){v1.z, v1.w};
        v2f rl = __builtin_elementwise_fma(a0v, v0l, a1v * v1l);
        v2f rh = __builtin_elementwise_fma(a0v, v0h, a1v * v1h);
        float4 r = {rl.x, rl.y, rh.x, rh.y};
        outv[p * 256] = r;
    }
}

extern "C" void kernel_launch(void* const* d_in, const int* in_sizes, int n_in,
                              void* d_out, int out_size, void* d_ws, size_t ws_size,
                              hipStream_t stream) {
    const float* X  = (const float*)d_in[0];
    const float* E  = (const float*)d_in[1];
    const float* F  = (const float*)d_in[2];
    const float* G  = (const float*)d_in[3];
    const float* bx = (const float*)d_in[4];
    const float* by = (const float*)d_in[5];
    float* outp = (float*)d_out;
    trp_fused<<<dim3(NBLK), dim3(256), 0, stream>>>(X, E, F, G, bx, by, outp);
}